// Round 2
// baseline (317.293 us; speedup 1.0000x reference)
//
#include <hip/hip_runtime.h>

#define N_NODES 10000
#define N_EDGES 160000
#define IN_DIM 128
#define HID 16
#define HEADS 50
#define OUT_DIM 10
#define N_GRAPHS 8
#define NHID (HEADS * HID) /* 800 */

// ---- bf16 helpers (self-contained, RNE) ----
static __device__ __forceinline__ unsigned short f2bf(float f) {
    union { float f; unsigned u; } v; v.f = f;
    unsigned u = v.u;
    unsigned r = (u + 0x7fffu + ((u >> 16) & 1u)) >> 16;
    return (unsigned short)r;
}
static __device__ __forceinline__ float bf2f(unsigned short s) {
    union { unsigned u; float f; } v; v.u = ((unsigned)s) << 16;
    return v.f;
}

// ---- K1: xp_t[h][n][c] = (x(10000x128) @ W(128x800)) transposed to head-major, bf16 ----
__global__ __launch_bounds__(256) void gemm_kernel(const float* __restrict__ x,
                                                   const float* __restrict__ W,
                                                   unsigned short* __restrict__ xpt) {
    __shared__ float As[64][64];  // As[k][m]
    __shared__ float Bs[64][64];  // Bs[k][n]
    const int tid = threadIdx.x;
    const int m0 = blockIdx.y * 64;
    const int n0 = blockIdx.x * 64;
    const int tx = tid & 15, ty = tid >> 4;
    float acc[4][4] = {};
    const int am = tid & 63;
    const int ak = (tid >> 6) * 16;
    const int bn = (tid & 15) * 4;
    const int bk = tid >> 4;

    for (int kk = 0; kk < IN_DIM; kk += 64) {
        const int gm = m0 + am;
#pragma unroll
        for (int i = 0; i < 4; i++) {
            int k4 = ak + i * 4;
            float4 v = make_float4(0.f, 0.f, 0.f, 0.f);
            if (gm < N_NODES) v = *(const float4*)(x + gm * IN_DIM + kk + k4);
            As[k4 + 0][am] = v.x; As[k4 + 1][am] = v.y;
            As[k4 + 2][am] = v.z; As[k4 + 3][am] = v.w;
        }
#pragma unroll
        for (int i = 0; i < 4; i++) {
            int k = bk + i * 16;
            float4 v = make_float4(0.f, 0.f, 0.f, 0.f);
            if (n0 + bn < NHID) v = *(const float4*)(W + (kk + k) * NHID + n0 + bn);
            *(float4*)&Bs[k][bn] = v;
        }
        __syncthreads();
#pragma unroll
        for (int k = 0; k < 64; k++) {
            float4 a = *(const float4*)&As[k][ty * 4];
            float4 b = *(const float4*)&Bs[k][tx * 4];
            float av[4] = {a.x, a.y, a.z, a.w};
            float bv[4] = {b.x, b.y, b.z, b.w};
#pragma unroll
            for (int i = 0; i < 4; i++)
#pragma unroll
                for (int j = 0; j < 4; j++) acc[i][j] += av[i] * bv[j];
        }
        __syncthreads();
    }
    const int gn = n0 + tx * 4;
    const int h = gn >> 4;        // head
    const int c0 = gn & 15;       // channel base (multiple of 4)
#pragma unroll
    for (int i = 0; i < 4; i++) {
        int gm = m0 + ty * 4 + i;
        if (gm < N_NODES && gn < NHID) {
            ushort4 o;
            o.x = f2bf(acc[i][0]); o.y = f2bf(acc[i][1]);
            o.z = f2bf(acc[i][2]); o.w = f2bf(acc[i][3]);
            *(ushort4*)(xpt + ((h * N_NODES + gm) << 4) + c0) = o;  // 8B aligned
        }
    }
}

// ---- K2: as_t[h][n] = xp_t[h][n][:] . a_src[h][:]; ad_t likewise ----
__global__ __launch_bounds__(256) void alpha_kernel(const unsigned short* __restrict__ xpt,
                                                    const float* __restrict__ a_src,
                                                    const float* __restrict__ a_dst,
                                                    float* __restrict__ ast,
                                                    float* __restrict__ adt) {
    int tid = blockIdx.x * 256 + threadIdx.x;
    if (tid >= N_NODES * HEADS) return;
    int h = tid / N_NODES;  // head-major: coalesced reads and writes
    int n = tid % N_NODES;
    const uint4* row4 = (const uint4*)(xpt + ((h * N_NODES + n) << 4));
    uint4 r0 = row4[0], r1 = row4[1];
    unsigned uu[8] = {r0.x, r0.y, r0.z, r0.w, r1.x, r1.y, r1.z, r1.w};
    float s = 0.f, d = 0.f;
#pragma unroll
    for (int q = 0; q < 8; q++) {
        float v0 = bf2f((unsigned short)(uu[q] & 0xffffu));
        float v1 = bf2f((unsigned short)(uu[q] >> 16));
        s += v0 * a_src[h * HID + 2 * q] + v1 * a_src[h * HID + 2 * q + 1];
        d += v0 * a_dst[h * HID + 2 * q] + v1 * a_dst[h * HID + 2 * q + 1];
    }
    ast[tid] = s;
    adt[tid] = d;
}

// ---- K3: CSR build (count / scan / scatter) ----
__global__ void count_kernel(const int* __restrict__ ei, int* __restrict__ cnt) {
    int e = blockIdx.x * 256 + threadIdx.x;
    if (e < N_EDGES) atomicAdd(&cnt[ei[N_EDGES + e]], 1);
}

__global__ __launch_bounds__(1024) void scan_kernel(const int* __restrict__ cnt,
                                                    int* __restrict__ offs,
                                                    int* __restrict__ curs) {
    __shared__ int lds[1024];
    const int tid = threadIdx.x;
    const int base = tid * 10;
    int local[10];
    int s = 0;
#pragma unroll
    for (int i = 0; i < 10; i++) {
        int idx = base + i;
        int v = (idx < N_NODES) ? cnt[idx] : 0;
        local[i] = s;
        s += v;
    }
    lds[tid] = s;
    __syncthreads();
    for (int off = 1; off < 1024; off <<= 1) {
        int v = (tid >= off) ? lds[tid - off] : 0;
        __syncthreads();
        lds[tid] += v;
        __syncthreads();
    }
    int excl = lds[tid] - s;
    for (int i = 0; i < 10; i++) {
        int idx = base + i;
        if (idx < N_NODES) {
            int o = excl + local[i];
            offs[idx] = o;
            curs[idx] = o;
        }
    }
}

__global__ void scatter_kernel(const int* __restrict__ ei, int* __restrict__ curs,
                               int* __restrict__ ssrc) {
    int e = blockIdx.x * 256 + threadIdx.x;
    if (e < N_EDGES) {
        int d = ei[N_EDGES + e];
        int pos = atomicAdd(&curs[d], 1);
        ssrc[pos] = ei[e];
    }
}

// ---- K4: barrier-free per-(dst,head) aggregation; block = 4 waves = 4 heads ----
// grid (157, 13); wave w handles head by*4+w, lane handles dst bx*64+lane.
__global__ __launch_bounds__(256) void agg_kernel(const unsigned short* __restrict__ xpt,
                                                  const float* __restrict__ ast,
                                                  const float* __restrict__ adt,
                                                  const int* __restrict__ offs,
                                                  const int* __restrict__ cnt,
                                                  const int* __restrict__ ssrc,
                                                  float* __restrict__ hsum) {
    const int t = threadIdx.x;
    const int wave = t >> 6, lane = t & 63;
    const int h = blockIdx.y * 4 + wave;     // 0..51 (>=50 idle)
    const int dst = blockIdx.x * 64 + lane;  // 0..10047 (>=10000 idle)
    const bool hv = (h < HEADS), dv = (dst < N_NODES);
    float acc[16];
#pragma unroll
    for (int c = 0; c < 16; c++) acc[c] = 0.f;
    if (hv && dv) {
        const int start = offs[dst];
        const int deg = cnt[dst];
        const float adv = adt[h * N_NODES + dst];
        const float* ash = ast + h * N_NODES;
        const unsigned short* xph = xpt + (h * N_NODES << 4);
        float den = 0.f;
        for (int e = 0; e <= deg; e++) {  // e==deg -> self loop
            const int src = (e < deg) ? ssrc[start + e] : dst;
            float l = ash[src] + adv;
            l = (l > 0.f) ? l : 0.2f * l;  // leaky relu
            float w = __expf(l);           // no max-shift: logits bounded
            den += w;
            const uint4* p = (const uint4*)(xph + (src << 4));
            uint4 p0 = p[0], p1 = p[1];
            unsigned uu[8] = {p0.x, p0.y, p0.z, p0.w, p1.x, p1.y, p1.z, p1.w};
#pragma unroll
            for (int q = 0; q < 8; q++) {
                acc[2 * q + 0] += w * bf2f((unsigned short)(uu[q] & 0xffffu));
                acc[2 * q + 1] += w * bf2f((unsigned short)(uu[q] >> 16));
            }
        }
        const float invd = 1.f / den;  // den >= exp(self) > 0
#pragma unroll
        for (int c = 0; c < 16; c++) acc[c] *= invd;
    }
    // reduce the block's 4 heads into LDS, then one atomic set per (dst, c)
    __shared__ float red[64 * 17];  // +1 pad: lane*17 spreads banks
    for (int i = t; i < 64 * 17; i += 256) red[i] = 0.f;
    __syncthreads();
    if (hv && dv) {
#pragma unroll
        for (int c = 0; c < 16; c++) atomicAdd(&red[lane * 17 + c], acc[c]);
    }
    __syncthreads();
    {
        const int dl = t >> 2, c0 = (t & 3) * 4;
        const int d2 = blockIdx.x * 64 + dl;
        if (d2 < N_NODES) {
#pragma unroll
            for (int i = 0; i < 4; i++)
                atomicAdd(&hsum[(d2 << 4) + c0 + i], red[dl * 17 + c0 + i]);
        }
    }
}

// ---- K5: per-graph mean pool (+ head mean + bias) + FC. One block per graph. ----
__global__ __launch_bounds__(256) void pool_kernel(const float* __restrict__ hsum,
                                                   const int* __restrict__ batch,
                                                   const float* __restrict__ bias,
                                                   const float* __restrict__ fc_w,
                                                   const float* __restrict__ fc_b,
                                                   float* __restrict__ out) {
    const int g = blockIdx.x;
    const int t = threadIdx.x;
    // binary search [lo, hi) of nodes with batch == g (batch sorted)
    int a = 0, b = N_NODES;
    while (a < b) { int m = (a + b) >> 1; if (batch[m] < g) a = m + 1; else b = m; }
    const int lo = a;
    b = N_NODES;
    while (a < b) { int m = (a + b) >> 1; if (batch[m] < g + 1) a = m + 1; else b = m; }
    const int hi = a;
    const int cntn = hi - lo;
    float acc[16];
#pragma unroll
    for (int c = 0; c < 16; c++) acc[c] = 0.f;
    for (int n = lo + t; n < hi; n += 256) {
        const float4* r = (const float4*)(hsum + (n << 4));
        float4 v0 = r[0], v1 = r[1], v2 = r[2], v3 = r[3];
        acc[0] += v0.x; acc[1] += v0.y; acc[2] += v0.z; acc[3] += v0.w;
        acc[4] += v1.x; acc[5] += v1.y; acc[6] += v1.z; acc[7] += v1.w;
        acc[8] += v2.x; acc[9] += v2.y; acc[10] += v2.z; acc[11] += v2.w;
        acc[12] += v3.x; acc[13] += v3.y; acc[14] += v3.z; acc[15] += v3.w;
    }
    __shared__ float red[256][17];
#pragma unroll
    for (int c = 0; c < 16; c++) red[t][c] = acc[c];
    __syncthreads();
    for (int s = 128; s > 0; s >>= 1) {
        if (t < s)
#pragma unroll
            for (int c = 0; c < 16; c++) red[t][c] += red[t + s][c];
        __syncthreads();
    }
    __shared__ float pooled[16];
    if (t < 16) {
        float v = 0.f;
        if (cntn > 0) v = red[0][t] / ((float)cntn * (float)HEADS) + bias[t];
        pooled[t] = v;
    }
    __syncthreads();
    if (t < OUT_DIM) {
        float s = fc_b[t];
#pragma unroll
        for (int c = 0; c < HID; c++) s += pooled[c] * fc_w[c * OUT_DIM + t];
        out[g * OUT_DIM + t] = s;
    }
}

// ---- workspace layout (bytes) ----
#define XPT_OFF 0             /* 50*10000*16*2 = 16,000,000 */
#define AST_OFF 16000000      /* 50*10000*4    =  2,000,000 */
#define ADT_OFF 18000000      /* 50*10000*4    =  2,000,000 */
#define SSRC_OFF 20000000     /* 160000*4      =    640,000 */
#define OFFS_OFF 20640000     /* 10000*4       =     40,000 */
#define CURS_OFF 20680000     /* 10000*4       =     40,000 */
#define CNT_OFF 20720000      /* 10000*4       =     40,000  (zeroed) */
#define HSUM_OFF 20760000     /* 10000*16*4    =    640,000  (zeroed) */

extern "C" void kernel_launch(void* const* d_in, const int* in_sizes, int n_in,
                              void* d_out, int out_size, void* d_ws, size_t ws_size,
                              hipStream_t stream) {
    const float* x = (const float*)d_in[0];
    const int* ei = (const int*)d_in[1];
    const int* batch = (const int*)d_in[2];
    const float* W = (const float*)d_in[4];
    const float* a_src = (const float*)d_in[5];
    const float* a_dst = (const float*)d_in[6];
    const float* bias = (const float*)d_in[7];
    const float* fc_w = (const float*)d_in[8];
    const float* fc_b = (const float*)d_in[9];
    float* out = (float*)d_out;

    char* ws = (char*)d_ws;
    unsigned short* xpt = (unsigned short*)(ws + XPT_OFF);
    float* ast = (float*)(ws + AST_OFF);
    float* adt = (float*)(ws + ADT_OFF);
    int* ssrc = (int*)(ws + SSRC_OFF);
    int* offs = (int*)(ws + OFFS_OFF);
    int* curs = (int*)(ws + CURS_OFF);
    int* cntc = (int*)(ws + CNT_OFF);
    float* hsum = (float*)(ws + HSUM_OFF);

    // zero degree counts + hsum (contiguous)
    hipMemsetAsync(ws + CNT_OFF, 0, 40000 + 640000, stream);

    gemm_kernel<<<dim3((NHID + 63) / 64, (N_NODES + 63) / 64), 256, 0, stream>>>(x, W, xpt);
    alpha_kernel<<<(N_NODES * HEADS + 255) / 256, 256, 0, stream>>>(xpt, a_src, a_dst, ast, adt);
    count_kernel<<<(N_EDGES + 255) / 256, 256, 0, stream>>>(ei, cntc);
    scan_kernel<<<1, 1024, 0, stream>>>(cntc, offs, curs);
    scatter_kernel<<<(N_EDGES + 255) / 256, 256, 0, stream>>>(ei, curs, ssrc);
    agg_kernel<<<dim3((N_NODES + 63) / 64, (HEADS + 3) / 4), 256, 0, stream>>>(
        xpt, ast, adt, offs, cntc, ssrc, hsum);
    pool_kernel<<<N_GRAPHS, 256, 0, stream>>>(hsum, batch, bias, fc_w, fc_b, out);
}

// Round 4
// 278.447 us; speedup vs baseline: 1.1395x; 1.1395x over previous
//
#include <hip/hip_runtime.h>

#define N_NODES 10000
#define N_EDGES 160000
#define IN_DIM 128
#define HID 16
#define HEADS 50
#define OUT_DIM 10
#define N_GRAPHS 8
#define NHID (HEADS * HID) /* 800 */

// ---- bf16 helpers (self-contained, RNE) ----
static __device__ __forceinline__ unsigned short f2bf(float f) {
    union { float f; unsigned u; } v; v.f = f;
    unsigned u = v.u;
    unsigned r = (u + 0x7fffu + ((u >> 16) & 1u)) >> 16;
    return (unsigned short)r;
}
static __device__ __forceinline__ float bf2f(unsigned short s) {
    union { unsigned u; float f; } v; v.u = ((unsigned)s) << 16;
    return v.f;
}

// ---- K1: xp_t[h][n][c] = (x(10000x128) @ W(128x800)) head-major, bf16 ----
// 128x64 block tile, 8x4 per-thread tile: 3 b128 LDS reads per 32 FMA.
// grid.x = 13 (ceil(800/64)) — last block partially OOB, guarded.
__global__ __launch_bounds__(256) void gemm_kernel(const float* __restrict__ x,
                                                   const float* __restrict__ W,
                                                   unsigned short* __restrict__ xpt) {
    __shared__ float As[64][128];  // As[k][m]
    __shared__ float Bs[64][64];   // Bs[k][n]
    const int tid = threadIdx.x;
    const int m0 = blockIdx.y * 128;
    const int n0 = blockIdx.x * 64;
    const int tx = tid & 15, ty = tid >> 4;
    float acc[8][4] = {};
    const int am = tid & 127;         // A loader: m in tile
    const int akg = (tid >> 7) * 32;  // A loader: k group base (0 or 32)
    const int bn = (tid & 15) * 4;    // B loader: n in tile
    const int bk = tid >> 4;          // B loader: k row base

    for (int kk = 0; kk < IN_DIM; kk += 64) {
        const int gm = m0 + am;
#pragma unroll
        for (int i = 0; i < 8; i++) {
            int k4 = akg + i * 4;
            float4 v = make_float4(0.f, 0.f, 0.f, 0.f);
            if (gm < N_NODES) v = *(const float4*)(x + gm * IN_DIM + kk + k4);
            As[k4 + 0][am] = v.x; As[k4 + 1][am] = v.y;
            As[k4 + 2][am] = v.z; As[k4 + 3][am] = v.w;
        }
#pragma unroll
        for (int i = 0; i < 4; i++) {
            int k = bk + i * 16;
            float4 v = make_float4(0.f, 0.f, 0.f, 0.f);
            if (n0 + bn < NHID) v = *(const float4*)(W + (kk + k) * NHID + n0 + bn);
            *(float4*)&Bs[k][bn] = v;
        }
        __syncthreads();
#pragma unroll
        for (int k = 0; k < 64; k++) {
            float4 a0 = *(const float4*)&As[k][ty * 8];
            float4 a1 = *(const float4*)&As[k][ty * 8 + 4];
            float4 b = *(const float4*)&Bs[k][tx * 4];
            float av[8] = {a0.x, a0.y, a0.z, a0.w, a1.x, a1.y, a1.z, a1.w};
            float bv[4] = {b.x, b.y, b.z, b.w};
#pragma unroll
            for (int i = 0; i < 8; i++)
#pragma unroll
                for (int j = 0; j < 4; j++) acc[i][j] += av[i] * bv[j];
        }
        __syncthreads();
    }
    const int gn = n0 + tx * 4;
    const int h = gn >> 4;   // head
    const int c0 = gn & 15;  // channel base
    if (gn < NHID) {
#pragma unroll
        for (int i = 0; i < 8; i++) {
            int gm = m0 + ty * 8 + i;
            if (gm < N_NODES) {
                ushort4 o;
                o.x = f2bf(acc[i][0]); o.y = f2bf(acc[i][1]);
                o.z = f2bf(acc[i][2]); o.w = f2bf(acc[i][3]);
                *(ushort4*)(xpt + ((h * N_NODES + gm) << 4) + c0) = o;  // 8B aligned
            }
        }
    }
}

// ---- K2: as_t[h][n] = xp_t[h][n][:] . a_src[h][:]; ad_t likewise ----
__global__ __launch_bounds__(256) void alpha_kernel(const unsigned short* __restrict__ xpt,
                                                    const float* __restrict__ a_src,
                                                    const float* __restrict__ a_dst,
                                                    float* __restrict__ ast,
                                                    float* __restrict__ adt) {
    int tid = blockIdx.x * 256 + threadIdx.x;
    if (tid >= N_NODES * HEADS) return;
    int h = tid / N_NODES;  // head-major: coalesced reads and writes
    int n = tid % N_NODES;
    const uint4* row4 = (const uint4*)(xpt + ((h * N_NODES + n) << 4));
    uint4 r0 = row4[0], r1 = row4[1];
    unsigned uu[8] = {r0.x, r0.y, r0.z, r0.w, r1.x, r1.y, r1.z, r1.w};
    float s = 0.f, d = 0.f;
#pragma unroll
    for (int q = 0; q < 8; q++) {
        float v0 = bf2f((unsigned short)(uu[q] & 0xffffu));
        float v1 = bf2f((unsigned short)(uu[q] >> 16));
        s += v0 * a_src[h * HID + 2 * q] + v1 * a_src[h * HID + 2 * q + 1];
        d += v0 * a_dst[h * HID + 2 * q] + v1 * a_dst[h * HID + 2 * q + 1];
    }
    ast[tid] = s;
    adt[tid] = d;
}

// ---- K3: CSR build (count / scan / scatter) ----
__global__ void count_kernel(const int* __restrict__ ei, int* __restrict__ cnt) {
    int e = blockIdx.x * 256 + threadIdx.x;
    if (e < N_EDGES) atomicAdd(&cnt[ei[N_EDGES + e]], 1);
}

__global__ __launch_bounds__(1024) void scan_kernel(const int* __restrict__ cnt,
                                                    int* __restrict__ offs,
                                                    int* __restrict__ curs) {
    __shared__ int lds[1024];
    const int tid = threadIdx.x;
    const int base = tid * 10;
    int local[10];
    int s = 0;
#pragma unroll
    for (int i = 0; i < 10; i++) {
        int idx = base + i;
        int v = (idx < N_NODES) ? cnt[idx] : 0;
        local[i] = s;
        s += v;
    }
    lds[tid] = s;
    __syncthreads();
    for (int off = 1; off < 1024; off <<= 1) {
        int v = (tid >= off) ? lds[tid - off] : 0;
        __syncthreads();
        lds[tid] += v;
        __syncthreads();
    }
    int excl = lds[tid] - s;
    for (int i = 0; i < 10; i++) {
        int idx = base + i;
        if (idx < N_NODES) {
            int o = excl + local[i];
            offs[idx] = o;
            curs[idx] = o;
        }
    }
}

__global__ void scatter_kernel(const int* __restrict__ ei, int* __restrict__ curs,
                               int* __restrict__ ssrc) {
    int e = blockIdx.x * 256 + threadIdx.x;
    if (e < N_EDGES) {
        int d = ei[N_EDGES + e];
        int pos = atomicAdd(&curs[d], 1);
        ssrc[pos] = ei[e];
    }
}

// ---- K4: XCD-partitioned aggregation ----
// blockIdx.x & 7 -> intended XCD (round-robin dispatch heuristic). Group k owns
// heads [k*50/8, (k+1)*50/8) (6-7 heads, ~2.2 MB of xpt -> L2-resident).
// Block = 4 waves x 64 dsts; wave w loops heads hstart+w, +4, ... accumulating
// the cross-head sum in registers. Then LDS-reduce 4 waves + global atomics.
__global__ __launch_bounds__(256) void agg_kernel(const unsigned short* __restrict__ xpt,
                                                  const float* __restrict__ ast,
                                                  const float* __restrict__ adt,
                                                  const int* __restrict__ offs,
                                                  const int* __restrict__ cnt,
                                                  const int* __restrict__ ssrc,
                                                  float* __restrict__ hsum) {
    const int t = threadIdx.x;
    const int wave = t >> 6, lane = t & 63;
    const int grp = blockIdx.x & 7;  // intended XCD
    const int db = blockIdx.x >> 3;  // dst-block 0..156
    const int dst = db * 64 + lane;
    const int hstart = (grp * HEADS) >> 3;
    const int hend = ((grp + 1) * HEADS) >> 3;
    const bool dv = (dst < N_NODES);
    float sum[16];
#pragma unroll
    for (int c = 0; c < 16; c++) sum[c] = 0.f;
    if (dv) {
        const int start = offs[dst];
        const int deg = cnt[dst];
        for (int h = hstart + wave; h < hend; h += 4) {
            float acc[16];
#pragma unroll
            for (int c = 0; c < 16; c++) acc[c] = 0.f;
            float den = 0.f;
            const float adv = adt[h * N_NODES + dst];
            const float* ash = ast + h * N_NODES;
            const unsigned short* xph = xpt + ((size_t)(h * N_NODES) << 4);
            for (int e = 0; e <= deg; e++) {  // e==deg -> self loop
                const int src = (e < deg) ? ssrc[start + e] : dst;
                float l = ash[src] + adv;
                l = (l > 0.f) ? l : 0.2f * l;  // leaky relu
                float w = __expf(l);           // no max-shift: logits bounded
                den += w;
                const uint4* p = (const uint4*)(xph + ((size_t)src << 4));
                uint4 p0 = p[0], p1 = p[1];
                unsigned uu[8] = {p0.x, p0.y, p0.z, p0.w, p1.x, p1.y, p1.z, p1.w};
#pragma unroll
                for (int q = 0; q < 8; q++) {
                    acc[2 * q + 0] += w * bf2f((unsigned short)(uu[q] & 0xffffu));
                    acc[2 * q + 1] += w * bf2f((unsigned short)(uu[q] >> 16));
                }
            }
            const float invd = 1.f / den;  // den >= exp(self) > 0
#pragma unroll
            for (int c = 0; c < 16; c++) sum[c] += acc[c] * invd;
        }
    }
    // reduce the block's 4 waves (disjoint heads, same dst per lane)
    __shared__ float red[64 * 17];  // stride 17: odd -> conflict-light
    for (int i = t; i < 64 * 17; i += 256) red[i] = 0.f;
    __syncthreads();
    if (dv) {
#pragma unroll
        for (int c = 0; c < 16; c++) atomicAdd(&red[lane * 17 + c], sum[c]);
    }
    __syncthreads();
    {
        const int dl = t >> 2, c0 = (t & 3) * 4;
        const int d2 = db * 64 + dl;
        if (d2 < N_NODES) {
#pragma unroll
            for (int i = 0; i < 4; i++)
                atomicAdd(&hsum[(d2 << 4) + c0 + i], red[dl * 17 + c0 + i]);
        }
    }
}

// ---- K5: per-graph mean pool (+ head mean + bias) + FC. One block per graph. ----
__global__ __launch_bounds__(256) void pool_kernel(const float* __restrict__ hsum,
                                                   const int* __restrict__ batch,
                                                   const float* __restrict__ bias,
                                                   const float* __restrict__ fc_w,
                                                   const float* __restrict__ fc_b,
                                                   float* __restrict__ out) {
    const int g = blockIdx.x;
    const int t = threadIdx.x;
    int a = 0, b = N_NODES;
    while (a < b) { int m = (a + b) >> 1; if (batch[m] < g) a = m + 1; else b = m; }
    const int lo = a;
    b = N_NODES;
    while (a < b) { int m = (a + b) >> 1; if (batch[m] < g + 1) a = m + 1; else b = m; }
    const int hi = a;
    const int cntn = hi - lo;
    float acc[16];
#pragma unroll
    for (int c = 0; c < 16; c++) acc[c] = 0.f;
    for (int n = lo + t; n < hi; n += 256) {
        const float4* r = (const float4*)(hsum + (n << 4));
        float4 v0 = r[0], v1 = r[1], v2 = r[2], v3 = r[3];
        acc[0] += v0.x; acc[1] += v0.y; acc[2] += v0.z; acc[3] += v0.w;
        acc[4] += v1.x; acc[5] += v1.y; acc[6] += v1.z; acc[7] += v1.w;
        acc[8] += v2.x; acc[9] += v2.y; acc[10] += v2.z; acc[11] += v2.w;
        acc[12] += v3.x; acc[13] += v3.y; acc[14] += v3.z; acc[15] += v3.w;
    }
    __shared__ float red[256][17];
#pragma unroll
    for (int c = 0; c < 16; c++) red[t][c] = acc[c];
    __syncthreads();
    for (int s = 128; s > 0; s >>= 1) {
        if (t < s)
#pragma unroll
            for (int c = 0; c < 16; c++) red[t][c] += red[t + s][c];
        __syncthreads();
    }
    __shared__ float pooled[16];
    if (t < 16) {
        float v = 0.f;
        if (cntn > 0) v = red[0][t] / ((float)cntn * (float)HEADS) + bias[t];
        pooled[t] = v;
    }
    __syncthreads();
    if (t < OUT_DIM) {
        float s = fc_b[t];
#pragma unroll
        for (int c = 0; c < HID; c++) s += pooled[c] * fc_w[c * OUT_DIM + t];
        out[g * OUT_DIM + t] = s;
    }
}

// ---- workspace layout (bytes) ----
#define XPT_OFF 0             /* 50*10000*16*2 = 16,000,000 */
#define AST_OFF 16000000      /* 50*10000*4    =  2,000,000 */
#define ADT_OFF 18000000      /* 50*10000*4    =  2,000,000 */
#define SSRC_OFF 20000000     /* 160000*4      =    640,000 */
#define OFFS_OFF 20640000     /* 10000*4       =     40,000 */
#define CURS_OFF 20680000     /* 10000*4       =     40,000 */
#define CNT_OFF 20720000      /* 10000*4       =     40,000  (zeroed) */
#define HSUM_OFF 20760000     /* 10000*16*4    =    640,000  (zeroed) */

extern "C" void kernel_launch(void* const* d_in, const int* in_sizes, int n_in,
                              void* d_out, int out_size, void* d_ws, size_t ws_size,
                              hipStream_t stream) {
    const float* x = (const float*)d_in[0];
    const int* ei = (const int*)d_in[1];
    const int* batch = (const int*)d_in[2];
    const float* W = (const float*)d_in[4];
    const float* a_src = (const float*)d_in[5];
    const float* a_dst = (const float*)d_in[6];
    const float* bias = (const float*)d_in[7];
    const float* fc_w = (const float*)d_in[8];
    const float* fc_b = (const float*)d_in[9];
    float* out = (float*)d_out;

    char* ws = (char*)d_ws;
    unsigned short* xpt = (unsigned short*)(ws + XPT_OFF);
    float* ast = (float*)(ws + AST_OFF);
    float* adt = (float*)(ws + ADT_OFF);
    int* ssrc = (int*)(ws + SSRC_OFF);
    int* offs = (int*)(ws + OFFS_OFF);
    int* curs = (int*)(ws + CURS_OFF);
    int* cntc = (int*)(ws + CNT_OFF);
    float* hsum = (float*)(ws + HSUM_OFF);

    // zero degree counts + hsum (contiguous)
    hipMemsetAsync(ws + CNT_OFF, 0, 40000 + 640000, stream);

    gemm_kernel<<<dim3((NHID + 63) / 64, (N_NODES + 127) / 128), 256, 0, stream>>>(x, W, xpt);
    alpha_kernel<<<(N_NODES * HEADS + 255) / 256, 256, 0, stream>>>(xpt, a_src, a_dst, ast, adt);
    count_kernel<<<(N_EDGES + 255) / 256, 256, 0, stream>>>(ei, cntc);
    scan_kernel<<<1, 1024, 0, stream>>>(cntc, offs, curs);
    scatter_kernel<<<(N_EDGES + 255) / 256, 256, 0, stream>>>(ei, curs, ssrc);
    agg_kernel<<<8 * ((N_NODES + 63) / 64), 256, 0, stream>>>(xpt, ast, adt, offs, cntc, ssrc, hsum);
    pool_kernel<<<N_GRAPHS, 256, 0, stream>>>(hsum, batch, bias, fc_w, fc_b, out);
}